// Round 19
// baseline (80.114 us; speedup 1.0000x reference)
//
#include <hip/hip_runtime.h>
#include <hip/hip_bf16.h>
#include <math.h>

// Leapfrog on SPD(32), eigh-free, inverse-free, barrier-free MFMA version.
//   U = S·P ; Ut = P·S (independent) ; H = U·U (= S·P·S·P = S·G)
//   M = 0.02·U - 2e-4·H  (= 2DT·S·pi_half)
//   E = exp(M^T) Taylor-3 (first stage f32 VALU: X3 = I + M/3)
//   Sigma_new = sym(S·E) + 1e-8 I
// TWO matrices per wave with matrix-1 staged via ASYNC global_load_lds
// (16B width) into a per-wave 8KB LDS region — doubles per-wave HBM
// bytes-in-flight at ZERO VGPR cost (R18 showed +24 VGPR for the same
// prefetch collapses occupancy 37->20%). Staging is in FRAGMENT order:
// per-lane global source = that lane's fragment chunk, LDS dest = linear
// lane*16 (glds HW pattern), so readback at base+l*16 is conflict-free
// stride-16B. m0 computes from register loads exactly as R14. Ordering:
// m0's conversion waits drain vmem in-order (glds issued first), plus an
// explicit ~free vmcnt(0) before m0's stores; sched_barrier(0) fences the
// m1 ds_reads (compiler may otherwise hoist them). LDS bounce region is
// per-wave and reused m0->m1: __threadfence_block() between writes/reads
// and between m0 reads / m1 writes (the R15-class race).
// All validated pieces: trunc v_perm packs, LDS-bounce sym epilogue with
// contiguous nt stores, cached loads, U^2-head, Taylor-3 f32 first stage,
// independent 3-chain tail, v_permlane32_swap_b32 (swap32(x,y):
// x.lanes[32:63] <-> y.lanes[0:31]), no setprio, no launch-bounds cap.

typedef unsigned int u32;
typedef __attribute__((ext_vector_type(8))) short bf16x8;
typedef __attribute__((ext_vector_type(16))) float f32x16;

#define FPAD 33    // f32 row stride of sym buffer: 33 mod 32 == 1 -> conflict-free
#define STG  2048  // floats per wave staging region (8 KB: S1 at 0, P1 at 1024)

union U4 { u32 u[4]; bf16x8 v; };

__device__ __forceinline__ bf16x8 mk8(u32 a, u32 b, u32 c, u32 d) {
    U4 t; t.u[0] = a; t.u[1] = b; t.u[2] = c; t.u[3] = d; return t.v;
}

// pack bf16(x),bf16(y) (truncated) into one u32: low16 = x, high16 = y
__device__ __forceinline__ u32 pkt(float x, float y) {
    return __builtin_amdgcn_perm(__float_as_uint(y), __float_as_uint(x), 0x07060302u);
}

__device__ __forceinline__ float asfloat(u32 b) {
    union { u32 u; float f; } c; c.u = b; return c.f;
}

__device__ __forceinline__ f32x16 zero16() {
    f32x16 z;
#pragma unroll
    for (int i = 0; i < 16; ++i) z[i] = 0.f;
    return z;
}

struct Frag8 { u32 r[8]; };

// v_permlane32_swap_b32: x.lanes[32:63] <-> y.lanes[0:31]
__device__ __forceinline__ void swap32(u32& x, u32& y) {
    asm("v_permlane32_swap_b32 %0, %1" : "+v"(x), "+v"(y));
}

__device__ __forceinline__ void xchg(const u32* p, Frag8& B) {
    { u32 x = p[0], y = p[2]; swap32(x, y); B.r[0] = x; B.r[2] = y; }
    { u32 x = p[1], y = p[3]; swap32(x, y); B.r[1] = x; B.r[3] = y; }
    { u32 x = p[4], y = p[6]; swap32(x, y); B.r[4] = x; B.r[6] = y; }
    { u32 x = p[5], y = p[7]; swap32(x, y); B.r[5] = x; B.r[7] = y; }
}

__device__ __forceinline__ void bconv(const f32x16& X, Frag8& B) {
    u32 p[8];
#pragma unroll
    for (int i = 0; i < 8; ++i) p[i] = pkt(X[2*i], X[2*i+1]);
    xchg(p, B);
}

__device__ __forceinline__ void bconv_s(const f32x16& X, float scale, Frag8& B) {
    u32 p[8];
#pragma unroll
    for (int i = 0; i < 8; ++i) p[i] = pkt(X[2*i] * scale, X[2*i+1] * scale);
    xchg(p, B);
}

__device__ __forceinline__ void bconv_split(const f32x16& X, Frag8& Bh, Frag8& Bl) {
    u32 p[8], q[8];
#pragma unroll
    for (int i = 0; i < 8; ++i) {
        const float x = X[2*i], y = X[2*i+1];
        p[i] = pkt(x, y);
        const float lx = x - asfloat(p[i] << 16);
        const float ly = y - asfloat(p[i] & 0xffff0000u);
        q[i] = pkt(lx, ly);
    }
    xchg(p, Bh);
    xchg(q, Bl);
}

__device__ __forceinline__ f32x16 MFMA1(const u32* a, const u32* b, f32x16 acc) {
    return __builtin_amdgcn_mfma_f32_32x32x16_bf16(
        mk8(a[0], a[1], a[2], a[3]), mk8(b[0], b[1], b[2], b[3]), acc, 0, 0, 0);
}

__device__ __forceinline__ f32x16 matmul(const Frag8& A, const Frag8& B, f32x16 acc) {
    acc = MFMA1(A.r,     B.r,     acc);   // k = 0..15
    acc = MFMA1(A.r + 4, B.r + 4, acc);   // k = 16..31
    return acc;
}

// full per-matrix compute + epilogue (R14 body). The free vmcnt(0) sits
// between the bounce-write fence and the store loop: at that point the
// only possibly-outstanding vmem ops are the async glds (m0 call) or
// long-drained stores (m1 call) -> cheap, and it guarantees staging
// completion before the caller's subsequent ds_reads.
__device__ __forceinline__ void do_matrix(const float4* sv, const float4* pv,
                                          float phc, float qhc, int bn,
                                          int fr, int h, int l,
                                          float* __restrict__ sy,
                                          const f32x16& If,
                                          float* __restrict__ out)
{
    Frag8 FS, FSl, FP;
#pragma unroll
    for (int i = 0; i < 4; ++i) {
        const float4 s = sv[i];
        const float4 p = pv[i];
        const u32 ha = pkt(s.x, s.y);
        const u32 hb = pkt(s.z, s.w);
        FS.r[2*i]   = ha;
        FS.r[2*i+1] = hb;
        const float lx = s.x - asfloat(ha << 16);
        const float ly = s.y - asfloat(ha & 0xffff0000u);
        const float lz = s.z - asfloat(hb << 16);
        const float lw = s.w - asfloat(hb & 0xffff0000u);
        FSl.r[2*i]   = pkt(lx, ly);
        FSl.r[2*i+1] = pkt(lz, lw);
        FP.r[2*i]   = pkt(p.x, p.y);
        FP.r[2*i+1] = pkt(p.z, p.w);
    }

    // ---- U = S·P ; Ut = P·S (independent) ; H = U·U = S·P·S·P ----
    f32x16 U  = matmul(FS, FP, zero16());
    f32x16 Ut = matmul(FP, FS, zero16());
    Frag8 BU;  bconv(U,  BU);
    Frag8 BUt; bconv(Ut, BUt);              // as A-operand represents U
    f32x16 H = matmul(BUt, BU, zero16());

    // ---- M = 2DT·U − 2DT²·H ;  X3 = I + M/3 (f32 VALU) ----
    f32x16 M, X;
#pragma unroll
    for (int i = 0; i < 16; ++i) {
        M[i] = 0.02f * U[i] - 2e-4f * H[i];
        X[i] = If[i] + (1.0f / 3.0f) * M[i];
    }
    Frag8 FM; bconv(M, FM);                 // A-frag of M^T

    // ---- X2 = I + (1/2)·M^T·X3 ; X1 = I + M^T·X2 ----
    {
        Frag8 BX; bconv_s(X, 0.5f, BX);
        X = matmul(FM, BX, If);
    }
    {
        Frag8 BX; bconv(X, BX);
        X = matmul(FM, BX, If);
    }

    // ---- Y^T = S·X, hi/lo split, three independent 2-MFMA chains ----
    Frag8 BE, BEl;
    bconv_split(X, BE, BEl);
    f32x16 Y1 = matmul(FS,  BE,  zero16());
    f32x16 Y2 = matmul(FSl, BE,  zero16());
    f32x16 Y3 = matmul(FS,  BEl, zero16());

    // ---- sym + eps·I via LDS bounce (fence: writes before reads) ----
#pragma unroll
    for (int i = 0; i < 16; ++i) {
        const int r = (i & 3) + 8 * (i >> 2) + 4 * h;
        sy[r * FPAD + fr] = Y1[i] + Y2[i] + Y3[i];
    }
    __threadfence_block();
    asm volatile("s_waitcnt vmcnt(0)" ::: "memory");  // drain glds (m0) — ~free
    const size_t obase = (size_t)bn * 1027;
#pragma unroll
    for (int k = 0; k < 16; ++k) {
        const int idx = k * 64 + l;
        const int r = idx >> 5, c = idx & 31;
        const float a = sy[r * FPAD + c];
        const float b = sy[c * FPAD + r];
        float v = 0.5f * (a + b);
        if (r == c) v += 1e-8f;
        __builtin_nontemporal_store(v, &out[obase + idx]);
    }

    // ---- phi retraction (lanes 0-2, double; floor-based mod 2pi) ----
    if (l < 3) {
        const double TWO_PI = 6.283185307179586476925287;
        const double PI_    = 3.141592653589793238462643;
        const double c0 = (double)__shfl(phc, 0, 64) + 0.01 * (double)__shfl(qhc, 0, 64);
        const double c1 = (double)__shfl(phc, 1, 64) + 0.01 * (double)__shfl(qhc, 1, 64);
        const double c2 = (double)__shfl(phc, 2, 64) + 0.01 * (double)__shfl(qhc, 2, 64);
        const double me = (l == 0) ? c0 : (l == 1) ? c1 : c2;
        const double theta = sqrt(c0 * c0 + c1 * c1 + c2 * c2);
        const double ts = theta > 1e-12 ? theta : 1e-12;
        const double k2 = floor(theta * (1.0 / TWO_PI));
        const double tw = theta - k2 * TWO_PI;
        double t, sgn;
        if (tw > PI_) { t = TWO_PI - tw; sgn = -1.0; }
        else          { t = tw;          sgn = 1.0;  }
        const double rmax = PI_ - 0.01;
        if (t > rmax) t = rmax;
        const double f = sgn * t / ts;
        __builtin_nontemporal_store((float)(me * f), &out[obase + 1024 + l]);
    }
}

__global__ __launch_bounds__(256)
void leapfrog_fused(const float* __restrict__ Sg, const float* __restrict__ Pg,
                    const float* __restrict__ phig, const float* __restrict__ piphig,
                    float* __restrict__ out, int total)
{
    __shared__ __align__(16) float symb[4 * 32 * FPAD];
    __shared__ __align__(16) float stage[4 * STG];

    const int w   = threadIdx.x >> 6;
    const int l   = threadIdx.x & 63;
    const int bn0 = blockIdx.x * 8 + w * 2;
    if (bn0 >= total) return;           // wave-uniform; no __syncthreads anywhere
    const int bn1   = bn0 + 1;
    const bool has1 = (bn1 < total);
    const int bn1s  = has1 ? bn1 : bn0;

    float* sy  = symb  + w * 32 * FPAD;
    float* stw = stage + w * STG;       // wave-uniform staging base

    const int fr = l & 31;
    const int h  = l >> 5;

    // ---- 1. ASYNC stage matrix 1 (S,P) into LDS, fragment order:
    //         per-lane src = this lane's fragment chunk j; LDS dest =
    //         stw + j*1KB + lane*16 (glds linear pattern). ----
    {
        const size_t g1 = (size_t)bn1s * 1024;
        const float* S1 = Sg + g1 + fr * 32 + h * 8;
        const float* P1 = Pg + g1 + fr * 32 + h * 8;
        const int OFF[4] = {0, 4, 16, 20};
#pragma unroll
        for (int j = 0; j < 4; ++j) {
            __builtin_amdgcn_global_load_lds(
                (const __attribute__((address_space(1))) u32*)(S1 + OFF[j]),
                (__attribute__((address_space(3))) u32*)(stw + j * 256), 16, 0, 0);
            __builtin_amdgcn_global_load_lds(
                (const __attribute__((address_space(1))) u32*)(P1 + OFF[j]),
                (__attribute__((address_space(3))) u32*)(stw + 1024 + j * 256), 16, 0, 0);
        }
    }

    // ---- 2. matrix 0 register loads + both matrices' phi ----
    const size_t g0 = (size_t)bn0 * 1024;
    const float* S0 = Sg + g0 + fr * 32 + h * 8;
    const float* P0 = Pg + g0 + fr * 32 + h * 8;
    float4 s0v[4], p0v[4];
    s0v[0] = *(const float4*)(S0 +  0); s0v[1] = *(const float4*)(S0 +  4);
    s0v[2] = *(const float4*)(S0 + 16); s0v[3] = *(const float4*)(S0 + 20);
    p0v[0] = *(const float4*)(P0 +  0); p0v[1] = *(const float4*)(P0 +  4);
    p0v[2] = *(const float4*)(P0 + 16); p0v[3] = *(const float4*)(P0 + 20);
    float ph0 = 0.f, qh0 = 0.f, ph1 = 0.f, qh1 = 0.f;
    if (l < 3) {
        ph0 = phig[3 * bn0 + l];  qh0 = piphig[3 * bn0 + l];
        ph1 = phig[3 * bn1s + l]; qh1 = piphig[3 * bn1s + l];
    }

    // identity in D-layout: row (i&3)+8*(i>>2)+4h, col fr (shared)
    f32x16 If;
#pragma unroll
    for (int i = 0; i < 16; ++i)
        If[i] = (((i & 3) + 8 * (i >> 2) + 4 * h) == fr) ? 1.f : 0.f;

    // ---- 3. matrix 0 (staging loads in flight underneath; do_matrix's
    //         internal vmcnt(0) guarantees staging completion) ----
    do_matrix(s0v, p0v, ph0, qh0, bn0, fr, h, l, sy, If, out);

    if (has1) {
        // ---- 4. matrix 1 from LDS staging ----
        __builtin_amdgcn_sched_barrier(0);   // don't hoist ds_reads above the vmcnt
        float4 s1v[4], p1v[4];
#pragma unroll
        for (int j = 0; j < 4; ++j) {
            s1v[j] = *(const float4*)(stw + j * 256 + l * 4);
            p1v[j] = *(const float4*)(stw + 1024 + j * 256 + l * 4);
        }
        // order m0's bounce READS before m1's bounce WRITES (same region)
        __threadfence_block();
        do_matrix(s1v, p1v, ph1, qh1, bn1, fr, h, l, sy, If, out);
    }
}

extern "C" void kernel_launch(void* const* d_in, const int* in_sizes, int n_in,
                              void* d_out, int out_size, void* d_ws, size_t ws_size,
                              hipStream_t stream)
{
    const float* Sg     = (const float*)d_in[0];
    const float* Pg     = (const float*)d_in[1];
    const float* phig   = (const float*)d_in[2];
    const float* piphig = (const float*)d_in[3];
    float* out = (float*)d_out;

    const int total = in_sizes[0] / 1024;   // B*N = 32768 matrices

    leapfrog_fused<<<(total + 7) / 8, 256, 0, stream>>>(Sg, Pg, phig, piphig, out, total);
}

// Round 20
// 68.842 us; speedup vs baseline: 1.1637x; 1.1637x over previous
//
#include <hip/hip_runtime.h>
#include <hip/hip_bf16.h>
#include <math.h>

// Leapfrog on SPD(32), eigh-free, inverse-free, barrier-free MFMA version.
//   U = S·P ; Ut = P·S (independent) ; H = U·U (= S·P·S·P = S·G)
//   M = 0.02·U - 2e-4·H  (= 2DT·S·pi_half)
//   E = exp(M^T) Taylor-3 (X3 = I + M/3 in f32 VALU; 2 MFMA stages with
//   the +I applied as VALU diagonal adds — NOT a persistent If array)
//   Sigma_new = sym(S·E) + 1e-8 I
// R14 skeleton + REGISTER DIET: gfx950's VGPR/AGPR file is unified, and
// rocprof's VGPR_Count excludes the AGPR side — the f32x16 accumulators
// (If,U,Ut,H,M,X,Y1..Y3 ~ 144 f32) are what pinned occupancy at 3
// waves/SIMD (512/~170) across all prior rounds. Diet: (1) no persistent
// If — diagonal rematerialized per use site; (2) tail serialized into ONE
// accumulator (-32 regs, ~150cy); (3) head unchanged. Target peak unified
// ~85-100 -> 5-6 waves/SIMD.
// Also adds the MANDATORY __threadfence_block() in the LDS bounce (reads
// consume other lanes' writes — invisible to per-thread alias analysis;
// R15 proved the compiler may reorder; R14 passed by codegen luck).
// All validated pieces: trunc v_perm packs, LDS-bounce sym epilogue with
// contiguous nt stores, cached loads, U^2-head, Taylor-3 f32 first stage,
// v_permlane32_swap_b32 (swap32(x,y): x.lanes[32:63] <-> y.lanes[0:31]),
// no setprio, no launch-bounds cap, 256-thread blocks (16/1024-wave
// blocks and all multi-matrix-per-wave variants measured worse R7-R19).

typedef unsigned int u32;
typedef __attribute__((ext_vector_type(8))) short bf16x8;
typedef __attribute__((ext_vector_type(16))) float f32x16;

#define FPAD 33   // f32 row stride of sym buffer: 33 mod 32 == 1 -> conflict-free

union U4 { u32 u[4]; bf16x8 v; };

__device__ __forceinline__ bf16x8 mk8(u32 a, u32 b, u32 c, u32 d) {
    U4 t; t.u[0] = a; t.u[1] = b; t.u[2] = c; t.u[3] = d; return t.v;
}

// pack bf16(x),bf16(y) (truncated) into one u32: low16 = x, high16 = y
__device__ __forceinline__ u32 pkt(float x, float y) {
    return __builtin_amdgcn_perm(__float_as_uint(y), __float_as_uint(x), 0x07060302u);
}

__device__ __forceinline__ float asfloat(u32 b) {
    union { u32 u; float f; } c; c.u = b; return c.f;
}

__device__ __forceinline__ f32x16 zero16() {
    f32x16 z;
#pragma unroll
    for (int i = 0; i < 16; ++i) z[i] = 0.f;
    return z;
}

// D-layout row of acc element i for this lane: (i&3) + 8*(i>>2) + 4*h; col = fr.
// diag contribution is 1.0 where row==col — rematerializable (cmp+cndmask),
// deliberately NOT stored as a persistent 16-reg identity fragment.
__device__ __forceinline__ float diagf(int i, int h, int fr) {
    return (((i & 3) + 8 * (i >> 2) + 4 * h) == fr) ? 1.f : 0.f;
}

struct Frag8 { u32 r[8]; };

// v_permlane32_swap_b32: x.lanes[32:63] <-> y.lanes[0:31]
__device__ __forceinline__ void swap32(u32& x, u32& y) {
    asm("v_permlane32_swap_b32 %0, %1" : "+v"(x), "+v"(y));
}

// packed-pair regs p[8] (D-layout pairs) -> B-fragment order.
__device__ __forceinline__ void xchg(const u32* p, Frag8& B) {
    { u32 x = p[0], y = p[2]; swap32(x, y); B.r[0] = x; B.r[2] = y; }
    { u32 x = p[1], y = p[3]; swap32(x, y); B.r[1] = x; B.r[3] = y; }
    { u32 x = p[4], y = p[6]; swap32(x, y); B.r[4] = x; B.r[6] = y; }
    { u32 x = p[5], y = p[7]; swap32(x, y); B.r[5] = x; B.r[7] = y; }
}

__device__ __forceinline__ void bconv(const f32x16& X, Frag8& B) {
    u32 p[8];
#pragma unroll
    for (int i = 0; i < 8; ++i) p[i] = pkt(X[2*i], X[2*i+1]);
    xchg(p, B);
}

__device__ __forceinline__ void bconv_s(const f32x16& X, float scale, Frag8& B) {
    u32 p[8];
#pragma unroll
    for (int i = 0; i < 8; ++i) p[i] = pkt(X[2*i] * scale, X[2*i+1] * scale);
    xchg(p, B);
}

__device__ __forceinline__ void bconv_split(const f32x16& X, Frag8& Bh, Frag8& Bl) {
    u32 p[8], q[8];
#pragma unroll
    for (int i = 0; i < 8; ++i) {
        const float x = X[2*i], y = X[2*i+1];
        p[i] = pkt(x, y);
        const float lx = x - asfloat(p[i] << 16);
        const float ly = y - asfloat(p[i] & 0xffff0000u);
        q[i] = pkt(lx, ly);
    }
    xchg(p, Bh);
    xchg(q, Bl);
}

__device__ __forceinline__ f32x16 MFMA1(const u32* a, const u32* b, f32x16 acc) {
    return __builtin_amdgcn_mfma_f32_32x32x16_bf16(
        mk8(a[0], a[1], a[2], a[3]), mk8(b[0], b[1], b[2], b[3]), acc, 0, 0, 0);
}

__device__ __forceinline__ f32x16 matmul(const Frag8& A, const Frag8& B, f32x16 acc) {
    acc = MFMA1(A.r,     B.r,     acc);   // k = 0..15
    acc = MFMA1(A.r + 4, B.r + 4, acc);   // k = 16..31
    return acc;
}

__global__ __launch_bounds__(256)
void leapfrog_fused(const float* __restrict__ Sg, const float* __restrict__ Pg,
                    const float* __restrict__ phig, const float* __restrict__ piphig,
                    float* __restrict__ out, int total)
{
    __shared__ __align__(16) float symb[4 * 32 * FPAD];

    const int w  = threadIdx.x >> 6;
    const int l  = threadIdx.x & 63;
    const int bn = blockIdx.x * 4 + w;
    if (bn >= total) return;            // wave-uniform; kernel has no barriers

    float* sy = symb + w * 32 * FPAD;

    const int fr = l & 31;
    const int h  = l >> 5;
    const size_t gbase = (size_t)bn * 1024;

    // ---- fragment loads straight from global; phi prefetched alongside ----
    const float* Srow = Sg + gbase + fr * 32 + h * 8;
    const float* Prow = Pg + gbase + fr * 32 + h * 8;
    const float4 sv[4] = { *(const float4*)(Srow +  0), *(const float4*)(Srow +  4),
                           *(const float4*)(Srow + 16), *(const float4*)(Srow + 20) };
    const float4 pv[4] = { *(const float4*)(Prow +  0), *(const float4*)(Prow +  4),
                           *(const float4*)(Prow + 16), *(const float4*)(Prow + 20) };
    // phi inputs: lanes 0-2 each handle one component in the epilogue
    float phc = 0.f, qhc = 0.f;
    if (l < 3) { phc = phig[3 * bn + l]; qhc = piphig[3 * bn + l]; }

    Frag8 FS, FSl, FP;
#pragma unroll
    for (int i = 0; i < 4; ++i) {
        const float4 s = sv[i];
        const float4 p = pv[i];
        const u32 ha = pkt(s.x, s.y);
        const u32 hb = pkt(s.z, s.w);
        FS.r[2*i]   = ha;
        FS.r[2*i+1] = hb;
        const float lx = s.x - asfloat(ha << 16);
        const float ly = s.y - asfloat(ha & 0xffff0000u);
        const float lz = s.z - asfloat(hb << 16);
        const float lw = s.w - asfloat(hb & 0xffff0000u);
        FSl.r[2*i]   = pkt(lx, ly);
        FSl.r[2*i+1] = pkt(lz, lw);
        FP.r[2*i]   = pkt(p.x, p.y);
        FP.r[2*i+1] = pkt(p.z, p.w);
    }

    // ---- U = S·P ; Ut = P·S (independent chains) ; H = U·U = S·P·S·P ----
    f32x16 U  = matmul(FS, FP, zero16());
    f32x16 Ut = matmul(FP, FS, zero16());
    Frag8 BU;  bconv(U,  BU);
    Frag8 BUt; bconv(Ut, BUt);              // as A-operand represents U
    f32x16 H = matmul(BUt, BU, zero16());

    // ---- M = 2DT·U − 2DT²·H ;  X3 = I + M/3 (f32 VALU, diag inline) ----
    f32x16 M, X;
#pragma unroll
    for (int i = 0; i < 16; ++i) {
        M[i] = 0.02f * U[i] - 2e-4f * H[i];
        X[i] = diagf(i, h, fr) + (1.0f / 3.0f) * M[i];
    }
    Frag8 FM; bconv(M, FM);                 // A-frag of M^T

    // ---- X2 = I + (1/2)·M^T·X3 ; X1 = I + M^T·X2 (MFMA into zero, +I in
    //      VALU — keeps no persistent identity fragment alive) ----
    {
        Frag8 BX; bconv_s(X, 0.5f, BX);
        X = matmul(FM, BX, zero16());
#pragma unroll
        for (int i = 0; i < 16; ++i) X[i] += diagf(i, h, fr);
    }
    {
        Frag8 BX; bconv(X, BX);
        X = matmul(FM, BX, zero16());
#pragma unroll
        for (int i = 0; i < 16; ++i) X[i] += diagf(i, h, fr);
    }

    // ---- Y^T = S·X, hi/lo split, ONE serial accumulator (reg diet) ----
    Frag8 BE, BEl;
    bconv_split(X, BE, BEl);
    f32x16 Y = matmul(FS,  BEl, zero16());
    Y        = matmul(FSl, BE,  Y);
    Y        = matmul(FS,  BE,  Y);

    // ---- sym + eps·I via LDS bounce. Reads consume OTHER lanes' writes:
    //      fence REQUIRED (R15-class race; DS pipe in-order per wave so
    //      pinning instruction order suffices; regions are per-wave). ----
#pragma unroll
    for (int i = 0; i < 16; ++i) {
        const int r = (i & 3) + 8 * (i >> 2) + 4 * h;
        sy[r * FPAD + fr] = Y[i];
    }
    __threadfence_block();                  // order bounce writes before reads
    const size_t obase = (size_t)bn * 1027;
#pragma unroll
    for (int k = 0; k < 16; ++k) {
        const int idx = k * 64 + l;
        const int r = idx >> 5, c = idx & 31;
        const float a = sy[r * FPAD + c];
        const float b = sy[c * FPAD + r];
        float v = 0.5f * (a + b);
        if (r == c) v += 1e-8f;
        __builtin_nontemporal_store(v, &out[obase + idx]);
    }

    // ---- fused phi retraction (lanes 0-2, double; floor-based mod 2pi) ----
    if (l < 3) {
        const double TWO_PI = 6.283185307179586476925287;
        const double PI_    = 3.141592653589793238462643;
        const double c0 = (double)__shfl(phc, 0, 64) + 0.01 * (double)__shfl(qhc, 0, 64);
        const double c1 = (double)__shfl(phc, 1, 64) + 0.01 * (double)__shfl(qhc, 1, 64);
        const double c2 = (double)__shfl(phc, 2, 64) + 0.01 * (double)__shfl(qhc, 2, 64);
        const double me = (l == 0) ? c0 : (l == 1) ? c1 : c2;
        const double theta = sqrt(c0 * c0 + c1 * c1 + c2 * c2);
        const double ts = theta > 1e-12 ? theta : 1e-12;
        const double k2 = floor(theta * (1.0 / TWO_PI));
        const double tw = theta - k2 * TWO_PI;          // fmod(theta, 2pi), theta >= 0
        double t, sgn;
        if (tw > PI_) { t = TWO_PI - tw; sgn = -1.0; }
        else          { t = tw;          sgn = 1.0;  }
        const double rmax = PI_ - 0.01;
        if (t > rmax) t = rmax;
        const double f = sgn * t / ts;
        __builtin_nontemporal_store((float)(me * f), &out[obase + 1024 + l]);
    }
}

extern "C" void kernel_launch(void* const* d_in, const int* in_sizes, int n_in,
                              void* d_out, int out_size, void* d_ws, size_t ws_size,
                              hipStream_t stream)
{
    const float* Sg     = (const float*)d_in[0];
    const float* Pg     = (const float*)d_in[1];
    const float* phig   = (const float*)d_in[2];
    const float* piphig = (const float*)d_in[3];
    float* out = (float*)d_out;

    const int total = in_sizes[0] / 1024;   // B*N = 32768 matrices

    leapfrog_fused<<<(total + 3) / 4, 256, 0, stream>>>(Sg, Pg, phig, piphig, out, total);
}